// Round 2
// baseline (120.791 us; speedup 1.0000x reference)
//
#include <hip/hip_runtime.h>

// out[r] = SCALE * (dot(x[r,:], wcol) + bsum), wcol[i] = sum_o W[o,i], bsum = sum(b)
// x [8192,2048] f32, W [2048,2048] f32, b [2048] f32, out [8192] f32.
#define DIM   2048
#define NROW  8192
#define SCALE 0.1f

// ws layout (floats): ws[0..DIM-1] = wcol (atomic accumulators, pre-zeroed via
// hipMemsetAsync), ws[DIM] = bsum.

// --- Kernel 1: column sums of W + bsum ---
// grid.x = 257. Blocks 0..255: col-slice = b&1 (256 float4 cols), row-chunk =
// b>>1 (16 rows), 64 KB read each -> full-chip streaming pass over W.
// Block 256: reduce b -> ws[DIM].
__global__ __launch_bounds__(256) void colsum_kernel(const float* __restrict__ W,
                                                     const float* __restrict__ b,
                                                     float* __restrict__ ws) {
    const int blk = blockIdx.x;
    const int t = threadIdx.x;

    if (blk == 256) {                      // bsum block
        float s = 0.0f;
#pragma unroll
        for (int k = 0; k < DIM / 256; ++k) s += b[k * 256 + t];
#pragma unroll
        for (int off = 32; off > 0; off >>= 1) s += __shfl_down(s, off, 64);
        __shared__ float part[4];
        if ((t & 63) == 0) part[t >> 6] = s;
        __syncthreads();
        if (t == 0) ws[DIM] = part[0] + part[1] + part[2] + part[3];
        return;
    }

    const int col4 = (blk & 1) * 256 + t;          // float4 column index
    const int row0 = (blk >> 1) * 16;              // 128 row-chunks x 16 rows
    const float4* __restrict__ W4 = (const float4*)W;

    float ax = 0.f, ay = 0.f, az = 0.f, aw = 0.f;
#pragma unroll
    for (int r = 0; r < 16; ++r) {
        float4 v = W4[(size_t)(row0 + r) * (DIM / 4) + col4];
        ax += v.x; ay += v.y; az += v.z; aw += v.w;
    }
    float* dst = ws + col4 * 4;
    atomicAdd(dst + 0, ax);
    atomicAdd(dst + 1, ay);
    atomicAdd(dst + 2, az);
    atomicAdd(dst + 3, aw);
}

// --- Kernel 2: one wave per row. lane reads 8 float4 of x (32 floats), 8
// float4 of wcol (L1-resident after first wave per CU), 6-step shuffle reduce.
// No LDS, no __syncthreads.
__global__ __launch_bounds__(256) void rowdot_kernel(const float* __restrict__ x,
                                                     const float* __restrict__ ws,
                                                     float* __restrict__ out) {
    const int row  = (int)((blockIdx.x * 256u + threadIdx.x) >> 6); // global wave id
    const int lane = threadIdx.x & 63;
    const float bsum = ws[DIM];                     // uniform, issued early

    const float4* __restrict__ xr = (const float4*)x + (size_t)row * (DIM / 4);
    const float4* __restrict__ wc = (const float4*)ws;

    float s = 0.0f;
#pragma unroll
    for (int j = 0; j < 8; ++j) {                   // 8 independent float4 pairs
        float4 xv = xr[j * 64 + lane];
        float4 wv = wc[j * 64 + lane];
        s += xv.x * wv.x + xv.y * wv.y + xv.z * wv.z + xv.w * wv.w;
    }
#pragma unroll
    for (int off = 32; off > 0; off >>= 1) s += __shfl_down(s, off, 64);

    if (lane == 0) out[row] = SCALE * (s + bsum);
}

extern "C" void kernel_launch(void* const* d_in, const int* in_sizes, int n_in,
                              void* d_out, int out_size, void* d_ws, size_t ws_size,
                              hipStream_t stream) {
    const float* x = (const float*)d_in[0];  // [8192, 2048]
    const float* W = (const float*)d_in[1];  // [2048, 2048]
    const float* b = (const float*)d_in[2];  // [2048]
    float* out = (float*)d_out;              // [8192]
    float* ws  = (float*)d_ws;

    // zero the wcol accumulators + bsum slot (ws is re-poisoned 0xAA each call)
    hipMemsetAsync(ws, 0, (DIM + 1) * sizeof(float), stream);

    colsum_kernel<<<257, 256, 0, stream>>>(W, b, ws);
    rowdot_kernel<<<NROW / 4, 256, 0, stream>>>(x, ws, out);  // 2048 blocks, 1 wave/row
}